// Round 4
// baseline (96.465 us; speedup 1.0000x reference)
//
#include <hip/hip_runtime.h>
#include <math.h>

#define THREADS 256

// 32 magnitude patterns of the D4 codebook, 2-bit codes per coordinate:
// c in {0,1,2}  =>  |g_i| = 0.5 + c.   mc = c0 | c1<<2 | c2<<4 | c3<<6
// Pattern order is exactly the reference's i8 = 0..31 enumeration.
// Score identity: s_p = (A-1) + sum_{c_i=1}(2a_i-2) + sum_{c_i=2}(4a_i-6).
#define MCP_LIST \
  0x00, 0x55, 0x50, 0x05, 0x44, 0x11, 0x14, 0x41, \
  0x01, 0x04, 0x10, 0x40, 0x54, 0x51, 0x45, 0x15, \
  0x02, 0x08, 0x20, 0x80, 0x09, 0x06, 0x12, 0x42, \
  0x21, 0x24, 0x18, 0x48, 0x81, 0x84, 0x90, 0x60

__device__ const unsigned d_MCP[32] = { MCP_LIST };   // runtime-indexed copy
constexpr unsigned h_MCP[32] = { MCP_LIST };           // compile-time folded copy

__global__ __launch_bounds__(THREADS)
void d4_fused_kernel(const float* __restrict__ X,
                     const float* __restrict__ grid,
                     const float* __restrict__ gnorm,
                     float* __restrict__ out, int n)
{
    const int i = blockIdx.x * blockDim.x + threadIdx.x;
    if (i >= n) return;

    const float4 xv = reinterpret_cast<const float4*>(X)[i];
    const float fx0 = xv.x, fx1 = xv.y, fx2 = xv.z, fx3 = xv.w;

    const float a0 = fabsf(fx0), a1 = fabsf(fx1), a2 = fabsf(fx2), a3 = fabsf(fx3);
    const float r0 = (a0 + a0) - 2.f, r1 = (a1 + a1) - 2.f;
    const float r2 = (a2 + a2) - 2.f, r3 = (a3 + a3) - 2.f;
    const float z0 = (a0 + a0 + a0 + a0) - 6.f, z1 = (a1 + a1 + a1 + a1) - 6.f;
    const float z2 = (a2 + a2 + a2 + a2) - 6.f, z3 = (a3 + a3 + a3 + a3) - 6.f;
    const float A = (a0 + a1) + (a2 + a3);
    const float base = A - 1.f;

    // flip costs m_i * a_i at the 3 magnitude levels
    const float h0 = 0.5f * a0, h1 = 0.5f * a1, h2 = 0.5f * a2, h3 = 0.5f * a3;
    const float t0 = h0 + a0, t1 = h1 + a1, t2 = h2 + a2, t3 = h3 + a3;  // 1.5a
    const float w0 = t0 + a0, w1 = t1 + a1, w2 = t2 + a2, w3 = t3 + a3;  // 2.5a

    const int s0 = (fx0 < 0.f) ? 1 : 0, s1 = (fx1 < 0.f) ? 1 : 0;
    const int s2 = (fx2 < 0.f) ? 1 : 0, s3 = (fx3 < 0.f) ? 1 : 0;
    const int qp = (s0 + s1 + s2 + s3) & 1;   // parity of # negative coords

    // parity-mismatch multiplier per pattern parity class (computed once):
    // rp==0 patterns pay 4*minp iff qp==1; rp==1 patterns iff qp==0.
    const float k0 = qp ? 4.f : 0.f;
    const float k1 = 4.f - k0;

    // Argmax with 5-bit pattern index packed into score mantissa LSBs.
    // Any two patterns within ~31ulp of each other have gap < delta and are
    // resolved by the exact slow path, so the perturbation is harmless.
    float best = -1e30f, second = -1e30f;
#pragma unroll
    for (int p = 0; p < 32; ++p) {
        const unsigned mc = h_MCP[p];
        const int c0 = mc & 3, c1 = (mc >> 2) & 3, c2 = (mc >> 4) & 3, c3 = (mc >> 6) & 3;

        float s = base;
        if (c0 == 1) s += r0; else if (c0 == 2) s += z0;
        if (c1 == 1) s += r1; else if (c1 == 2) s += z1;
        if (c2 == 1) s += r2; else if (c2 == 2) s += z2;
        if (c3 == 1) s += r3; else if (c3 == 2) s += z3;

        const float q0 = (c0 == 0) ? h0 : ((c0 == 1) ? t0 : w0);
        const float q1 = (c1 == 0) ? h1 : ((c1 == 1) ? t1 : w1);
        const float q2 = (c2 == 0) ? h2 : ((c2 == 1) ? t2 : w2);
        const float q3 = (c3 == 0) ? h3 : ((c3 == 1) ? t3 : w3);
        const float minp = fminf(fminf(q0, q1), fminf(q2, q3));

        const int rp = (c0 + c1 + c2 + c3) & 1;         // compile-time constant
        const float kk = rp ? k1 : k0;                  // register select, free
        float eff = s - kk * minp;                      // exact s when matched

        // pack pattern index into the 5 LSBs (31-p: ties prefer smaller p,
        // but true ties always route to the slow path anyway)
        eff = __uint_as_float((__float_as_uint(eff) & ~31u) | (unsigned)(31 - p));

        const float lo = fminf(best, eff);
        best = fmaxf(best, eff);
        second = fmaxf(second, lo);
    }

    const int bi = 31 - (int)(__float_as_uint(best) & 31u);

    // ---- reconstruct winning codeword + its reference index ----
    const unsigned mc = d_MCP[bi];
    const int c0 = mc & 3, c1 = (mc >> 2) & 3, c2 = (mc >> 4) & 3, c3 = (mc >> 6) & 3;
    const int rp = (c0 + c1 + c2 + c3) & 1;
    const bool flip = (rp != qp);

    const float p0 = (c0 == 0) ? h0 : ((c0 == 1) ? t0 : w0);
    const float p1 = (c1 == 0) ? h1 : ((c1 == 1) ? t1 : w1);
    const float p2 = (c2 == 0) ? h2 : ((c2 == 1) ? t2 : w2);
    const float p3 = (c3 == 0) ? h3 : ((c3 == 1) ? t3 : w3);
    int f = 0; float mp = p0;
    if (p1 < mp) { mp = p1; f = 1; }
    if (p2 < mp) { mp = p2; f = 2; }
    if (p3 < mp) { mp = p3; f = 3; }

    // two smallest of {p0..p3} (within-pattern runner-up bound)
    const float m01 = fminf(p0, p1), M01 = fmaxf(p0, p1);
    const float m23 = fminf(p2, p3), M23 = fmaxf(p2, p3);
    const float q1v = fminf(m01, m23);
    const float q2v = fminf(fmaxf(m01, m23), fminf(M01, M23));

    //  parity mismatch: second-best single flip  -> cost gap 4*(q2-q1)
    //  parity match:    cheapest double flip     -> cost 4*(q1+q2)
    const float within = flip ? 4.f * (q2v - q1v) : 4.f * (q1v + q2v);
    const float gap = fminf(best - second, within);
    // covers f32 rounding of my scores + numpy reference's + 2x the 31-ulp
    // index-packing perturbation (<= ~2.3e-5*A + 4e-5), with margin
    const float delta = 4e-5f * (A + 2.f);

    const bool n0 = ((s0 != 0) != (flip && f == 0));
    const bool n1 = ((s1 != 0) != (flip && f == 1));
    const bool n2 = ((s2 != 0) != (flip && f == 2));
    const bool n3 = ((s3 != 0) != (flip && f == 3));

    const float m0 = 0.5f + (float)c0, m1 = 0.5f + (float)c1;
    const float m2 = 0.5f + (float)c2, m3 = 0.5f + (float)c3;
    float4 g;
    g.x = n0 ? -m0 : m0;
    g.y = n1 ? -m1 : m1;
    g.z = n2 ? -m2 : m2;
    g.w = n3 ? -m3 : m3;

    // invert _code3_signs: b7=sign(g0), b6=sign(g1)^b7, b5=sign(g2)^b7
    const int b7 = n0 ? 1 : 0;
    const int b6 = (n1 ? 1 : 0) ^ b7;
    const int b5 = (n2 ? 1 : 0) ^ b7;
    int idx = bi | (b5 << 5) | (b6 << 6) | (b7 << 7);

    if (gap < delta) {
        // Rare (~1e-3): bit-exact emulation of the numpy reference.
        // Sequential f32 dot (no FMA), 2*dot - gn, first-wins argmax.
        // grid/gnorm are tiny and L2-resident; lanes here are broadcast-ish.
        float bexact = -INFINITY;
        int bk = 0;
        for (int k = 0; k < 256; ++k) {
            const float4 gk = reinterpret_cast<const float4*>(grid)[k];
            float d = __fmul_rn(fx0, gk.x);
            d = __fadd_rn(d, __fmul_rn(fx1, gk.y));
            d = __fadd_rn(d, __fmul_rn(fx2, gk.z));
            d = __fadd_rn(d, __fmul_rn(fx3, gk.w));
            const float sc = __fsub_rn(__fmul_rn(2.0f, d), gnorm[k]);
            if (sc > bexact) { bexact = sc; bk = k; }
        }
        const float4 gk = reinterpret_cast<const float4*>(grid)[bk];
        g = gk;
        idx = bk;
    }

    reinterpret_cast<float4*>(out)[i] = g;                 // output 0
    out[(size_t)4 * (size_t)n + (size_t)i] = (float)idx;   // output 1
}

extern "C" void kernel_launch(void* const* d_in, const int* in_sizes, int n_in,
                              void* d_out, int out_size, void* d_ws, size_t ws_size,
                              hipStream_t stream)
{
    const float* X = (const float*)d_in[0];
    const float* grid = (const float*)d_in[1];
    const float* gnorm = (const float*)d_in[2];
    float* out = (float*)d_out;
    const int n = in_sizes[0] / 4;
    const int blocks = (n + THREADS - 1) / THREADS;
    hipLaunchKernelGGL(d4_fused_kernel, dim3(blocks), dim3(THREADS), 0, stream,
                       X, grid, gnorm, out, n);
}

// Round 5
// 89.804 us; speedup vs baseline: 1.0742x; 1.0742x over previous
//
#include <hip/hip_runtime.h>
#include <math.h>

#define THREADS 256

// 32 magnitude patterns of the D4 codebook, 2-bit codes per coordinate:
// c in {0,1,2}  =>  |g_i| = 0.5 + c.   mc = c0 | c1<<2 | c2<<4 | c3<<6
// Pattern order is exactly the reference's i8 = 0..31 enumeration.
// Score identity: s_p = (A-1) + sum_{c_i=1}(2a_i-2) + sum_{c_i=2}(4a_i-6).
#define MCP_LIST \
  0x00, 0x55, 0x50, 0x05, 0x44, 0x11, 0x14, 0x41, \
  0x01, 0x04, 0x10, 0x40, 0x54, 0x51, 0x45, 0x15, \
  0x02, 0x08, 0x20, 0x80, 0x09, 0x06, 0x12, 0x42, \
  0x21, 0x24, 0x18, 0x48, 0x81, 0x84, 0x90, 0x60

__device__ const unsigned d_MCP[32] = { MCP_LIST };   // runtime-indexed copy
constexpr unsigned h_MCP[32] = { MCP_LIST };           // compile-time folded copy

__global__ __launch_bounds__(THREADS)
void d4_fused_kernel(const float* __restrict__ X,
                     const float* __restrict__ grid,
                     const float* __restrict__ gnorm,
                     float* __restrict__ out, int n)
{
    // Stage codebook for the (rare) exact slow path; broadcast reads later.
    __shared__ float4 sgrid[256];
    __shared__ float  sgn[256];
    sgrid[threadIdx.x] = reinterpret_cast<const float4*>(grid)[threadIdx.x];
    sgn[threadIdx.x]   = gnorm[threadIdx.x];
    __syncthreads();

    const int i = blockIdx.x * blockDim.x + threadIdx.x;
    if (i >= n) return;

    const float4 xv = reinterpret_cast<const float4*>(X)[i];
    const float fx0 = xv.x, fx1 = xv.y, fx2 = xv.z, fx3 = xv.w;

    const float a0 = fabsf(fx0), a1 = fabsf(fx1), a2 = fabsf(fx2), a3 = fabsf(fx3);
    // exact: u = 2a, v = 4a
    const float r0 = (a0 + a0) - 2.f, r1 = (a1 + a1) - 2.f;
    const float r2 = (a2 + a2) - 2.f, r3 = (a3 + a3) - 2.f;
    const float z0 = (a0 + a0 + a0 + a0) - 6.f, z1 = (a1 + a1 + a1 + a1) - 6.f;
    const float z2 = (a2 + a2 + a2 + a2) - 6.f, z3 = (a3 + a3 + a3 + a3) - 6.f;
    const float A = (a0 + a1) + (a2 + a3);
    const float base = A - 1.f;

    // magnitude-weighted "flip costs" m_i * a_i for the 3 levels
    const float h0 = 0.5f * a0, h1 = 0.5f * a1, h2 = 0.5f * a2, h3 = 0.5f * a3;
    const float t0 = h0 + a0, t1 = h1 + a1, t2 = h2 + a2, t3 = h3 + a3;  // 1.5a
    const float w0 = t0 + a0, w1 = t1 + a1, w2 = t2 + a2, w3 = t3 + a3;  // 2.5a

    const int s0 = (fx0 < 0.f) ? 1 : 0, s1 = (fx1 < 0.f) ? 1 : 0;
    const int s2 = (fx2 < 0.f) ? 1 : 0, s3 = (fx3 < 0.f) ? 1 : 0;
    const int qp = (s0 + s1 + s2 + s3) & 1;   // parity of # negative coords

    float best = -1e30f, second = -1e30f;
    int bi = 0;
#pragma unroll
    for (int p = 0; p < 32; ++p) {
        const unsigned mc = h_MCP[p];
        const int c0 = mc & 3, c1 = (mc >> 2) & 3, c2 = (mc >> 4) & 3, c3 = (mc >> 6) & 3;

        float s = base;
        if (c0 == 1) s += r0; else if (c0 == 2) s += z0;
        if (c1 == 1) s += r1; else if (c1 == 2) s += z1;
        if (c2 == 1) s += r2; else if (c2 == 2) s += z2;
        if (c3 == 1) s += r3; else if (c3 == 2) s += z3;

        const float q0 = (c0 == 0) ? h0 : ((c0 == 1) ? t0 : w0);
        const float q1 = (c1 == 0) ? h1 : ((c1 == 1) ? t1 : w1);
        const float q2 = (c2 == 0) ? h2 : ((c2 == 1) ? t2 : w2);
        const float q3 = (c3 == 0) ? h3 : ((c3 == 1) ? t3 : w3);
        const float minp = fminf(fminf(q0, q1), fminf(q2, q3));

        const int rp = (c0 + c1 + c2 + c3) & 1;         // required minus-parity
        const float eff = (rp != qp) ? (s - 4.f * minp) : s;

        if (eff > best) { second = best; best = eff; bi = p; }
        else if (eff > second) { second = eff; }
    }

    // ---- reconstruct winning codeword + its reference index ----
    {
        const unsigned mc = d_MCP[bi];
        const int c0 = mc & 3, c1 = (mc >> 2) & 3, c2 = (mc >> 4) & 3, c3 = (mc >> 6) & 3;
        const int rp = (c0 + c1 + c2 + c3) & 1;
        const bool flip = (rp != qp);

        const float p0 = (c0 == 0) ? h0 : ((c0 == 1) ? t0 : w0);
        const float p1 = (c1 == 0) ? h1 : ((c1 == 1) ? t1 : w1);
        const float p2 = (c2 == 0) ? h2 : ((c2 == 1) ? t2 : w2);
        const float p3 = (c3 == 0) ? h3 : ((c3 == 1) ? t3 : w3);
        int f = 0; float mp = p0;
        if (p1 < mp) { mp = p1; f = 1; }
        if (p2 < mp) { mp = p2; f = 2; }
        if (p3 < mp) { mp = p3; f = 3; }

        // two smallest of {p0..p3} (for the within-pattern runner-up bound)
        const float m01 = fminf(p0, p1), M01 = fmaxf(p0, p1);
        const float m23 = fminf(p2, p3), M23 = fmaxf(p2, p3);
        const float q1v = fminf(m01, m23);
        const float q2v = fminf(fmaxf(m01, m23), fminf(M01, M23));

        // runner-up within the winning pattern:
        //  parity mismatch: second-best single flip  -> cost gap 4*(q2-q1)
        //  parity match:    cheapest double flip     -> cost 4*(q1+q2)
        const float within = flip ? 4.f * (q2v - q1v) : 4.f * (q1v + q2v);
        const float gap = fminf(best - second, within);
        // covers worst-case f32 rounding of BOTH my scores and the numpy
        // reference's (each <= ~7e-7*(5A+27)); >2x safety margin
        const float delta = 8e-6f * (A + 6.f);

        const bool n0 = ((s0 != 0) != (flip && f == 0));
        const bool n1 = ((s1 != 0) != (flip && f == 1));
        const bool n2 = ((s2 != 0) != (flip && f == 2));
        const bool n3 = ((s3 != 0) != (flip && f == 3));

        const float m0 = 0.5f + (float)c0, m1 = 0.5f + (float)c1;
        const float m2 = 0.5f + (float)c2, m3 = 0.5f + (float)c3;
        float4 g;
        g.x = n0 ? -m0 : m0;
        g.y = n1 ? -m1 : m1;
        g.z = n2 ? -m2 : m2;
        g.w = n3 ? -m3 : m3;

        // invert _code3_signs: b7=sign(g0), b6=sign(g1)^b7, b5=sign(g2)^b7
        const int b7 = n0 ? 1 : 0;
        const int b6 = (n1 ? 1 : 0) ^ b7;
        const int b5 = (n2 ? 1 : 0) ^ b7;
        int idx = bi | (b5 << 5) | (b6 << 6) | (b7 << 7);

        if (gap < delta) {
            // Rare (~1e-4): bit-exact emulation of the numpy reference.
            // Sequential f32 dot (no FMA), 2*dot - gn, first-wins argmax.
            float bexact = -INFINITY;
            int bk = 0;
            for (int k = 0; k < 256; ++k) {
                const float4 gk = sgrid[k];
                float d = __fmul_rn(fx0, gk.x);
                d = __fadd_rn(d, __fmul_rn(fx1, gk.y));
                d = __fadd_rn(d, __fmul_rn(fx2, gk.z));
                d = __fadd_rn(d, __fmul_rn(fx3, gk.w));
                const float sc = __fsub_rn(__fmul_rn(2.0f, d), sgn[k]);
                if (sc > bexact) { bexact = sc; bk = k; }
            }
            g = sgrid[bk];
            idx = bk;
        }

        reinterpret_cast<float4*>(out)[i] = g;                 // output 0
        out[(size_t)4 * (size_t)n + (size_t)i] = (float)idx;   // output 1
    }
}

extern "C" void kernel_launch(void* const* d_in, const int* in_sizes, int n_in,
                              void* d_out, int out_size, void* d_ws, size_t ws_size,
                              hipStream_t stream)
{
    const float* X = (const float*)d_in[0];
    const float* grid = (const float*)d_in[1];
    const float* gnorm = (const float*)d_in[2];
    float* out = (float*)d_out;
    const int n = in_sizes[0] / 4;
    const int blocks = (n + THREADS - 1) / THREADS;
    hipLaunchKernelGGL(d4_fused_kernel, dim3(blocks), dim3(THREADS), 0, stream,
                       X, grid, gnorm, out, n);
}